// Round 4
// baseline (87.158 us; speedup 1.0000x reference)
//
#include <hip/hip_runtime.h>
#include <math.h>

// Net: 4 layers of out = 0.8*(x@W^T) + 0.2*max_i(W[o,i]*x[b,i]) + b
// B=1024, dims 256 -> 512 -> 512 -> 512 -> 1. All fp32.
//
// R4: FULLY FUSED single kernel. The net is row-independent (h[b,:] depends
// only on row b), so each block owns 4 batch rows and carries them through
// all 4 layers with activations ping-ponging in LDS (barrier per layer, no
// grid sync). 256 blocks x 512 threads = 1 block/CU. Each thread owns one
// output neuron o per layer and all 4 rows:
//   - W row streamed from global (thread-sequential -> L1-friendly;
//     1 MB/block/layer from L2, all-W fits in every XCD L2)
//   - h reads are wave-uniform LDS broadcasts (no bank pressure)
//   - dual accumulators per row = 8 independent FMA/max chains
// Layer 4 (O=1): per-wave shuffle reduce + cross-wave LDS combine.

#define NT   512
#define ROWS 4

__device__ __forceinline__ void layer_dense(
    const float (*__restrict__ hin)[512],
    float (*__restrict__ hout)[512],
    const float* __restrict__ W,
    const float* __restrict__ bias,
    int K, int t)
{
    const float* wrow = W + (size_t)t * K;

    float sa[ROWS], sb[ROWS], ma[ROWS], mb[ROWS];
    #pragma unroll
    for (int r = 0; r < ROWS; ++r) {
        sa[r] = 0.f; sb[r] = 0.f;
        ma[r] = -INFINITY; mb[r] = -INFINITY;
    }

    float4 wa = *(const float4*)&wrow[0];
    float4 wb = *(const float4*)&wrow[4];

    for (int k = 0; k < K; k += 8) {
        float4 na = wa, nb = wb;
        if (k + 8 < K) {                       // uniform branch (scalar)
            na = *(const float4*)&wrow[k + 8];
            nb = *(const float4*)&wrow[k + 12];
        }
        #pragma unroll
        for (int r = 0; r < ROWS; ++r) {
            float4 h0 = *(const float4*)&hin[r][k];      // wave-uniform bcast
            float4 h1 = *(const float4*)&hin[r][k + 4];
            float p;
            p = wa.x * h0.x; sa[r] += p; ma[r] = fmaxf(ma[r], p);
            p = wa.y * h0.y; sb[r] += p; mb[r] = fmaxf(mb[r], p);
            p = wa.z * h0.z; sa[r] += p; ma[r] = fmaxf(ma[r], p);
            p = wa.w * h0.w; sb[r] += p; mb[r] = fmaxf(mb[r], p);
            p = wb.x * h1.x; sa[r] += p; ma[r] = fmaxf(ma[r], p);
            p = wb.y * h1.y; sb[r] += p; mb[r] = fmaxf(mb[r], p);
            p = wb.z * h1.z; sa[r] += p; ma[r] = fmaxf(ma[r], p);
            p = wb.w * h1.w; sb[r] += p; mb[r] = fmaxf(mb[r], p);
        }
        wa = na; wb = nb;
    }

    const float bo = bias[t];
    #pragma unroll
    for (int r = 0; r < ROWS; ++r) {
        float s = sa[r] + sb[r];
        float m = fmaxf(ma[r], mb[r]);
        hout[r][t] = fmaf(0.2f, m, fmaf(0.8f, s, bo));
    }
}

__global__ __launch_bounds__(NT, 2) void net_fused(
    const float* __restrict__ x,
    const float* __restrict__ W1, const float* __restrict__ b1,
    const float* __restrict__ W2, const float* __restrict__ b2,
    const float* __restrict__ W3, const float* __restrict__ b3,
    const float* __restrict__ W4, const float* __restrict__ b4,
    float* __restrict__ out)
{
    __shared__ __align__(16) float ha[ROWS][512];
    __shared__ __align__(16) float hb[ROWS][512];
    __shared__ float red_s[8][ROWS];
    __shared__ float red_m[8][ROWS];

    const int t = threadIdx.x;
    const int row0 = blockIdx.x * ROWS;

    // stage x rows into ha: 4 rows x 256 = 512 float2, one per thread
    {
        const int r = t >> 7;               // 128 float2 per row
        const int c = (t & 127) * 2;
        float2 v = *(const float2*)&x[(size_t)(row0 + r) * 256 + c];
        ha[r][c]     = v.x;
        ha[r][c + 1] = v.y;
    }
    __syncthreads();

    layer_dense(ha, hb, W1, b1, 256, t);    // x  (ha) -> h1 (hb)
    __syncthreads();
    layer_dense(hb, ha, W2, b2, 512, t);    // h1 (hb) -> h2 (ha)
    __syncthreads();
    layer_dense(ha, hb, W3, b3, 512, t);    // h2 (ha) -> h3 (hb)
    __syncthreads();

    // ---- layer 4: O=1, reduce over o for each of the 4 rows ----
    const float w4 = W4[t];
    float ps[ROWS], pm[ROWS];
    #pragma unroll
    for (int r = 0; r < ROWS; ++r) {
        float p = w4 * hb[r][t];
        ps[r] = p;
        pm[r] = p;
    }
    #pragma unroll
    for (int off = 32; off; off >>= 1) {
        #pragma unroll
        for (int r = 0; r < ROWS; ++r) {
            ps[r] += __shfl_xor(ps[r], off, 64);
            pm[r] = fmaxf(pm[r], __shfl_xor(pm[r], off, 64));
        }
    }
    const int lane = t & 63;
    const int wave = t >> 6;
    if (lane == 0) {
        #pragma unroll
        for (int r = 0; r < ROWS; ++r) {
            red_s[wave][r] = ps[r];
            red_m[wave][r] = pm[r];
        }
    }
    __syncthreads();

    if (t < ROWS) {
        float s = red_s[0][t];
        float m = red_m[0][t];
        #pragma unroll
        for (int w = 1; w < 8; ++w) {
            s += red_s[w][t];
            m = fmaxf(m, red_m[w][t]);
        }
        out[row0 + t] = fmaf(0.2f, m, fmaf(0.8f, s, b4[0]));
    }
}

extern "C" void kernel_launch(void* const* d_in, const int* in_sizes, int n_in,
                              void* d_out, int out_size, void* d_ws, size_t ws_size,
                              hipStream_t stream)
{
    const float* x  = (const float*)d_in[0];
    const float* W1 = (const float*)d_in[1];
    const float* b1 = (const float*)d_in[2];
    const float* W2 = (const float*)d_in[3];
    const float* b2 = (const float*)d_in[4];
    const float* W3 = (const float*)d_in[5];
    const float* b3 = (const float*)d_in[6];
    const float* W4 = (const float*)d_in[7];
    const float* b4 = (const float*)d_in[8];

    net_fused<<<256, NT, 0, stream>>>(x, W1, b1, W2, b2, W3, b3, W4, b4,
                                      (float*)d_out);
}

// Round 5
// 66.273 us; speedup vs baseline: 1.3151x; 1.3151x over previous
//
#include <hip/hip_runtime.h>
#include <math.h>

// Net: 4 layers of out = 0.8*(x@W^T) + 0.2*max_i(W[o,i]*x[b,i]) + b
// B=1024, dims 256 -> 512 -> 512 -> 512 -> 1. All fp32.
//
// R5: fused single kernel (R4 structure) + COALESCED W via pre-transposed
// panel layout. R4 was VMEM-bound (VALUBusy 44%): thread t streamed W row t,
// so each wave-load touched 64 scattered cache lines. Now a prologue kernel
// writes WT[k4][o] (float4 = W[o][4k4..4k4+3]); in the main kernel lane o
// reads WT[k4][o] -> 64 consecutive float4s = 1KB fully-coalesced per
// wave-instr, streamed from L2 (W fits per-XCD L2). Group-of-4 register
// prefetch hides L2 latency. h stays in LDS as wave-uniform broadcasts.

#define NT   512
#define ROWS 4

// ws layout in float4 units
#define WT1_OFF 0
#define WT2_OFF 33280    // 32768 + 512 pad
#define WT3_OFF 99328    // 33280 + 65536 + 512 pad
// total 164864 float4 = 2.64 MB

__global__ __launch_bounds__(256) void transpose_all(
    const float* __restrict__ W1, const float* __restrict__ W2,
    const float* __restrict__ W3, float4* __restrict__ ws)
{
    const int tid = blockIdx.x * 256 + threadIdx.x;   // 0 .. 163839
    const float* W;
    float4* WT;
    int o, k4, K;
    if (tid < 32768) {                    // W1: O=512, K=256, K4=64
        W = W1; WT = ws + WT1_OFF; K = 256;
        o = tid >> 6; k4 = tid & 63;
    } else if (tid < 98304) {             // W2: O=512, K=512, K4=128
        const int idx = tid - 32768;
        W = W2; WT = ws + WT2_OFF; K = 512;
        o = idx >> 7; k4 = idx & 127;
    } else {                              // W3: O=512, K=512, K4=128
        const int idx = tid - 98304;
        W = W3; WT = ws + WT3_OFF; K = 512;
        o = idx >> 7; k4 = idx & 127;
    }
    // read coalesced along k; write scattered (stride O) -- one-time cost
    float4 v = *(const float4*)&W[(size_t)o * K + 4 * k4];
    WT[(size_t)k4 * 512 + o] = v;
}

// One layer: thread t owns output neuron o=t for ROWS batch rows.
// W from global (coalesced panel), h from LDS (wave-uniform broadcast).
__device__ __forceinline__ void layer_bcast(
    const float (*__restrict__ hin)[512],
    float (*__restrict__ hout)[512],
    const float4* __restrict__ WT,    // [K4][512]
    const float* __restrict__ bias,
    int K4, int t)
{
    float sa[ROWS], sb[ROWS], ma[ROWS], mb[ROWS];
    #pragma unroll
    for (int r = 0; r < ROWS; ++r) {
        sa[r] = 0.f; sb[r] = 0.f;
        ma[r] = -INFINITY; mb[r] = -INFINITY;
    }

    const float4* wp = WT + t;
    float4 w0 = wp[0];
    float4 w1 = wp[512];
    float4 w2 = wp[1024];
    float4 w3 = wp[1536];

    for (int kg = 0; kg < K4; kg += 4) {
        float4 n0 = w0, n1 = w1, n2 = w2, n3 = w3;
        if (kg + 4 < K4) {                 // uniform (scalar) branch
            const float4* q = wp + (size_t)(kg + 4) * 512;
            n0 = q[0];
            n1 = q[512];
            n2 = q[1024];
            n3 = q[1536];
        }
        #pragma unroll
        for (int j = 0; j < 4; ++j) {
            const float4 w = (j == 0) ? w0 : (j == 1) ? w1 : (j == 2) ? w2 : w3;
            const int k = (kg + j) * 4;
            #pragma unroll
            for (int r = 0; r < ROWS; ++r) {
                float4 h = *(const float4*)&hin[r][k];   // wave-uniform bcast
                float p;
                p = w.x * h.x; sa[r] += p; ma[r] = fmaxf(ma[r], p);
                p = w.y * h.y; sb[r] += p; mb[r] = fmaxf(mb[r], p);
                p = w.z * h.z; sa[r] += p; ma[r] = fmaxf(ma[r], p);
                p = w.w * h.w; sb[r] += p; mb[r] = fmaxf(mb[r], p);
            }
        }
        w0 = n0; w1 = n1; w2 = n2; w3 = n3;
    }

    const float bo = bias[t];
    #pragma unroll
    for (int r = 0; r < ROWS; ++r) {
        float s = sa[r] + sb[r];
        float m = fmaxf(ma[r], mb[r]);
        hout[r][t] = fmaf(0.2f, m, fmaf(0.8f, s, bo));
    }
}

__global__ __launch_bounds__(NT) void net_fused(
    const float* __restrict__ x,
    const float4* __restrict__ WT1, const float* __restrict__ b1,
    const float4* __restrict__ WT2, const float* __restrict__ b2,
    const float4* __restrict__ WT3, const float* __restrict__ b3,
    const float* __restrict__ W4,   const float* __restrict__ b4,
    float* __restrict__ out)
{
    __shared__ __align__(16) float ha[ROWS][512];
    __shared__ __align__(16) float hb[ROWS][512];
    __shared__ float red_s[8][ROWS];
    __shared__ float red_m[8][ROWS];

    const int t = threadIdx.x;
    const int row0 = blockIdx.x * ROWS;

    // stage x rows (4 x 256) into ha: one float2 per thread
    {
        const int r = t >> 7;
        const int c = (t & 127) * 2;
        float2 v = *(const float2*)&x[(size_t)(row0 + r) * 256 + c];
        ha[r][c]     = v.x;
        ha[r][c + 1] = v.y;
    }
    __syncthreads();

    layer_bcast(ha, hb, WT1, b1, 64,  t);   // x  -> h1
    __syncthreads();
    layer_bcast(hb, ha, WT2, b2, 128, t);   // h1 -> h2
    __syncthreads();
    layer_bcast(ha, hb, WT3, b3, 128, t);   // h2 -> h3
    __syncthreads();

    // ---- layer 4: O=1 ----
    const float w4 = W4[t];
    float ps[ROWS], pm[ROWS];
    #pragma unroll
    for (int r = 0; r < ROWS; ++r) {
        float p = w4 * hb[r][t];
        ps[r] = p;
        pm[r] = p;
    }
    #pragma unroll
    for (int off = 32; off; off >>= 1) {
        #pragma unroll
        for (int r = 0; r < ROWS; ++r) {
            ps[r] += __shfl_xor(ps[r], off, 64);
            pm[r] = fmaxf(pm[r], __shfl_xor(pm[r], off, 64));
        }
    }
    const int lane = t & 63;
    const int wave = t >> 6;
    if (lane == 0) {
        #pragma unroll
        for (int r = 0; r < ROWS; ++r) {
            red_s[wave][r] = ps[r];
            red_m[wave][r] = pm[r];
        }
    }
    __syncthreads();

    if (t < ROWS) {
        float s = red_s[0][t];
        float m = red_m[0][t];
        #pragma unroll
        for (int w = 1; w < 8; ++w) {
            s += red_s[w][t];
            m = fmaxf(m, red_m[w][t]);
        }
        out[row0 + t] = fmaf(0.2f, m, fmaf(0.8f, s, b4[0]));
    }
}

extern "C" void kernel_launch(void* const* d_in, const int* in_sizes, int n_in,
                              void* d_out, int out_size, void* d_ws, size_t ws_size,
                              hipStream_t stream)
{
    const float* x  = (const float*)d_in[0];
    const float* W1 = (const float*)d_in[1];
    const float* b1 = (const float*)d_in[2];
    const float* W2 = (const float*)d_in[3];
    const float* b2 = (const float*)d_in[4];
    const float* W3 = (const float*)d_in[5];
    const float* b3 = (const float*)d_in[6];
    const float* W4 = (const float*)d_in[7];
    const float* b4 = (const float*)d_in[8];

    float4* ws4 = (float4*)d_ws;

    transpose_all<<<640, 256, 0, stream>>>(W1, W2, W3, ws4);

    net_fused<<<256, NT, 0, stream>>>(
        x,
        ws4 + WT1_OFF, b1,
        ws4 + WT2_OFF, b2,
        ws4 + WT3_OFF, b3,
        W4, b4,
        (float*)d_out);
}